// Round 8
// baseline (156.421 us; speedup 1.0000x reference)
//
#include <hip/hip_runtime.h>
#include <stdint.h>

#define Td 1024
#define Hd 1024
#define Id 1024
#define Ed 8
#define Kd 2
#define Ld 4
#define Rd 16
#define Nd 2048
#define TKd (Td*Kd)

typedef __bf16 bf16x8 __attribute__((ext_vector_type(8)));
typedef float f32x4 __attribute__((ext_vector_type(4)));

__device__ __forceinline__ ushort f2bf(float f) {
    uint32_t u = __builtin_bit_cast(uint32_t, f);
    return (ushort)((u + 0x7fffu + ((u >> 16) & 1u)) >> 16);
}
__device__ __forceinline__ float bf2f(ushort u) {
    uint32_t x = ((uint32_t)u) << 16;
    return __builtin_bit_cast(float, x);
}
__device__ __forceinline__ bf16x8 pack8(float4 a, float4 b) {
    bf16x8 r;
    r[0] = (__bf16)a.x; r[1] = (__bf16)a.y; r[2] = (__bf16)a.z; r[3] = (__bf16)a.w;
    r[4] = (__bf16)b.x; r[5] = (__bf16)b.y; r[6] = (__bf16)b.z; r[7] = (__bf16)b.w;
    return r;
}

#define GLOAD_LDS16(g, l) __builtin_amdgcn_global_load_lds( \
    (const __attribute__((address_space(1))) uint32_t*)(const void*)(g), \
    (__attribute__((address_space(3))) uint32_t*)(void*)(l), 16, 0, 0)

// ---------------- k_prep: LoRA-B interleave (fp32) + gate_up LoRA-A proj + zero-out + route ----------------
#define CB 384     // interleave blocks: (64K + 32K) rows of 16 floats
#define TB 2048    // gate_up LoRA-A projection (one per pair)
#define ZB 1024    // out zeroing
#define PREP_BLOCKS (CB + TB + ZB + 1)

__global__ __launch_bounds__(256) void k_prep(
    const float* __restrict__ hid, const float* __restrict__ gb,
    const float* __restrict__ db, const float* __restrict__ ga,
    const float* __restrict__ sc, const int* __restrict__ tids,
    const int* __restrict__ lidx,
    float* __restrict__ gbbe, float* __restrict__ dbbe, float* __restrict__ tmp1e,
    float* __restrict__ out, int* __restrict__ sorted, int* __restrict__ offs)
{
    __shared__ float tr[Rd];
    __shared__ int cnt[Ed];
    __shared__ int cur[Ed];
    const int b = blockIdx.x, tid = threadIdx.x;

    if (b < CB) {
        // l-interleave LoRA-B, pure fp32 copy: gbbe[e][n][l*16+r] = gb[l][e][n][r]
        constexpr int GR = Ld * Ed * Nd;   // 65536
        int i = b * 256 + tid;
        const float* src; float* dst;
        if (i < GR) {
            int l = i >> 14, e = (i >> 11) & 7, n = i & 2047;
            src = gb + (size_t)i * 16;
            dst = gbbe + ((size_t)(e * Nd + n)) * 64 + l * 16;
        } else {
            int j = i - GR;
            int l = j >> 13, e = (j >> 10) & 7, h = j & 1023;
            src = db + (size_t)j * 16;
            dst = dbbe + ((size_t)(e * Id + h)) * 64 + l * 16;
        }
        float4 a0 = *(const float4*)(src);
        float4 a1 = *(const float4*)(src + 4);
        float4 a2 = *(const float4*)(src + 8);
        float4 a3 = *(const float4*)(src + 12);
        *(float4*)(dst)      = a0;
        *(float4*)(dst + 4)  = a1;
        *(float4*)(dst + 8)  = a2;
        *(float4*)(dst + 12) = a3;
    } else if (b < CB + TB) {
        // gate_up LoRA-A projection: tmp1e[p][l*16+r] = s*(Ag[l,e]@x[t]), zeros elsewhere
        const int p = b - CB;
        const int e = tids[p];
        const int l = lidx[p >> 1];
        const float s = sc[l];
        const int r = tid >> 4, q = tid & 15;
        const float* A = ga + (((size_t)l * Ed + e) * Rd + r) * 1024;
        const float* x = hid + (size_t)(p >> 1) * 1024;
        float sum = 0.f;
        #pragma unroll
        for (int i = 0; i < 16; ++i) {
            int h = q * 4 + 64 * i;
            float4 a = *(const float4*)(A + h);
            float4 v = *(const float4*)(x + h);
            sum += a.x * v.x + a.y * v.y + a.z * v.z + a.w * v.w;
        }
        sum += __shfl_xor(sum, 1); sum += __shfl_xor(sum, 2);
        sum += __shfl_xor(sum, 4); sum += __shfl_xor(sum, 8);
        if (q == 0) tr[r] = sum;
        __syncthreads();
        if (tid < 64) {
            tmp1e[(size_t)p * 64 + tid] = ((tid >> 4) == l) ? s * tr[tid & 15] : 0.f;
        }
    } else if (b < CB + TB + ZB) {
        int i = (b - CB - TB) * 256 + tid;
        ((float4*)out)[i] = make_float4(0.f, 0.f, 0.f, 0.f);
    } else {
        // route sort (single block, 8 pairs/thread)
        if (tid < Ed) cnt[tid] = 0;
        __syncthreads();
        int el[8];
        #pragma unroll
        for (int i = 0; i < 8; ++i) {
            el[i] = tids[tid + i * 256];
            atomicAdd(&cnt[el[i]], 1);
        }
        __syncthreads();
        if (tid == 0) {
            int s = 0;
            for (int e = 0; e < Ed; ++e) { offs[e] = s; cur[e] = s; s += cnt[e]; }
            offs[Ed] = s;
        }
        __syncthreads();
        #pragma unroll
        for (int i = 0; i < 8; ++i) {
            int pos = atomicAdd(&cur[el[i]], 1);
            sorted[pos] = tid + i * 256;
        }
    }
}

// ---------------- down LoRA-A projection (act bf16 input, bf16 out) ----------------
__global__ __launch_bounds__(256) void k_tmp_dn(
    const ushort* __restrict__ act, const float* __restrict__ da,
    const float* __restrict__ sc, const int* __restrict__ tids,
    const int* __restrict__ lidx, ushort* __restrict__ tmpde)
{
    const int p = blockIdx.x;
    const int e = tids[p];
    const int l = lidx[p >> 1];
    const float s = sc[l];
    const int tid = threadIdx.x;
    const int r = tid >> 4, q = tid & 15;
    const float* A = da + (((size_t)l * Ed + e) * Rd + r) * 1024;
    const ushort* x = act + (size_t)p * 1024;
    float sum = 0.f;
    #pragma unroll
    for (int i = 0; i < 8; ++i) {
        int h = q * 8 + 128 * i;
        float4 a0 = *(const float4*)(A + h);
        float4 a1 = *(const float4*)(A + h + 4);
        ushort4 v0 = *(const ushort4*)(x + h);
        ushort4 v1 = *(const ushort4*)(x + h + 4);
        sum += a0.x * bf2f(v0.x) + a0.y * bf2f(v0.y) + a0.z * bf2f(v0.z) + a0.w * bf2f(v0.w)
             + a1.x * bf2f(v1.x) + a1.y * bf2f(v1.y) + a1.z * bf2f(v1.z) + a1.w * bf2f(v1.w);
    }
    sum += __shfl_xor(sum, 1); sum += __shfl_xor(sum, 2);
    sum += __shfl_xor(sum, 4); sum += __shfl_xor(sum, 8);
    __shared__ float tr[Rd];
    if (q == 0) tr[r] = sum;
    __syncthreads();
    if (tid < 32) {
        int j0 = tid * 2;
        uint v = 0;
        if ((j0 >> 4) == l)
            v = (uint)f2bf(s * tr[j0 & 15]) | ((uint)f2bf(s * tr[(j0 + 1) & 15]) << 16);
        ((uint*)(tmpde + (size_t)p * 64))[tid] = v;
    }
}

// ---------------- gate_up GEMM: fp32 LDS staging (XOR-swizzled) + cvt-on-read + fused silu ----------------
__global__ __launch_bounds__(256) void k_gemm_gu(
    const float* __restrict__ hid, const float* __restrict__ w13,
    const float* __restrict__ tmp1e, const float* __restrict__ gbbe,
    ushort* __restrict__ act, const int* __restrict__ sorted,
    const int* __restrict__ offs)
{
    __shared__ float Af[2][128 * 32];
    __shared__ float Bf[2][128 * 32];
    const int tid = threadIdx.x, lane = tid & 63, wave = tid >> 6;
    const int wr = wave >> 1, wc = wave & 1;
    const int fr = lane & 15, q = lane >> 4;

    int off[Ed + 1], mt[Ed], pre[Ed + 1];
    #pragma unroll
    for (int e = 0; e <= Ed; ++e) off[e] = offs[e];
    pre[0] = 0;
    #pragma unroll
    for (int e = 0; e < Ed; ++e) {
        mt[e] = (off[e + 1] - off[e] + 127) / 128;
        pre[e + 1] = pre[e] + mt[e] * 16;          // 16 n-tiles of 64 gate-cols
    }
    const int tot = pre[Ed];

    for (int bid = blockIdx.x; bid < tot; bid += gridDim.x) {
        // bijective XCD-chunk swizzle (m204): XCD x gets a contiguous tau range
        int qq = tot >> 3, rr = tot & 7, x = bid & 7, ii = bid >> 3;
        int tau = (x < rr) ? x * (qq + 1) + ii : rr * (qq + 1) + (x - rr) * qq + ii;
        int e = 0;
        while (tau >= pre[e + 1]) ++e;
        int local = tau - pre[e];
        int nt = local / mt[e];                    // m-fastest: same-n tiles adjacent
        int mtile = local - nt * mt[e];
        const int m0 = off[e] + mtile * 128;
        const int mend = off[e + 1];
        const int n0 = nt * 64;

        // staging sources: slot s holds chunk (srow=s>>3, si=(s&7)^(srow&7)) -- inverse-swz source
        const float *as[4], *aes[4], *bs[4], *bes[4];
        #pragma unroll
        for (int r = 0; r < 4; ++r) {
            int s = r * 256 + tid;
            int srow = s >> 3, si = (s & 7) ^ (srow & 7);
            int aIdx = m0 + srow; if (aIdx > mend - 1) aIdx = mend - 1;
            int p = sorted[aIdx];
            as[r]  = hid + (size_t)(p >> 1) * 1024 + si * 4;
            aes[r] = tmp1e + (size_t)p * 64 + si * 4;
            int grow = (srow < 64) ? (n0 + srow) : (1024 + n0 + srow - 64);
            bs[r]  = w13 + ((size_t)e * Nd + grow) * 1024 + si * 4;
            bes[r] = gbbe + ((size_t)(e * Nd + grow)) * 64 + si * 4;
        }

        f32x4 ag[4][2] = {}, au[4][2] = {};

        auto stage = [&](int s, int buf) {
            if (s < 32) {
                int k0 = s * 32;
                #pragma unroll
                for (int r = 0; r < 4; ++r) {
                    GLOAD_LDS16(as[r] + k0, (char*)&Af[buf][0] + (r * 256 + wave * 64) * 16);
                    GLOAD_LDS16(bs[r] + k0, (char*)&Bf[buf][0] + (r * 256 + wave * 64) * 16);
                }
            } else {
                int k0 = (s - 32) * 32;
                #pragma unroll
                for (int r = 0; r < 4; ++r) {
                    GLOAD_LDS16(aes[r] + k0, (char*)&Af[buf][0] + (r * 256 + wave * 64) * 16);
                    GLOAD_LDS16(bes[r] + k0, (char*)&Bf[buf][0] + (r * 256 + wave * 64) * 16);
                }
            }
        };
        auto step = [&](int buf) {
            bf16x8 afv[4], bg[2], bu[2];
            #pragma unroll
            for (int mi = 0; mi < 4; ++mi) {
                int R = wr * 64 + mi * 16 + fr;
                const float4* base = (const float4*)&Af[buf][R * 32];
                afv[mi] = pack8(base[(2 * q) ^ (R & 7)], base[(2 * q + 1) ^ (R & 7)]);
            }
            #pragma unroll
            for (int ni = 0; ni < 2; ++ni) {
                int Rg = wc * 32 + ni * 16 + fr;
                const float4* bb = (const float4*)&Bf[buf][Rg * 32];
                bg[ni] = pack8(bb[(2 * q) ^ (Rg & 7)], bb[(2 * q + 1) ^ (Rg & 7)]);
                int Ru = Rg + 64;
                const float4* bu_ = (const float4*)&Bf[buf][Ru * 32];
                bu[ni] = pack8(bu_[(2 * q) ^ (Ru & 7)], bu_[(2 * q + 1) ^ (Ru & 7)]);
            }
            #pragma unroll
            for (int mi = 0; mi < 4; ++mi)
                #pragma unroll
                for (int ni = 0; ni < 2; ++ni) {
                    ag[mi][ni] = __builtin_amdgcn_mfma_f32_16x16x32_bf16(afv[mi], bg[ni], ag[mi][ni], 0, 0, 0);
                    au[mi][ni] = __builtin_amdgcn_mfma_f32_16x16x32_bf16(afv[mi], bu[ni], au[mi][ni], 0, 0, 0);
                }
        };

        stage(0, 0);
        __syncthreads();
        int buf = 0;
        for (int s = 0; s < 34; ++s) {            // 32 main + 2 LoRA-ext K-steps
            if (s < 33) stage(s + 1, buf ^ 1);
            step(buf);
            __syncthreads();
            buf ^= 1;
        }

        // epilogue: fused silu_and_mul -> act bf16
        const int rb = wr * 64 + (lane >> 4) * 4;
        #pragma unroll
        for (int mi = 0; mi < 4; ++mi) {
            #pragma unroll
            for (int j = 0; j < 4; ++j) {
                int sidx = m0 + rb + mi * 16 + j;
                if (sidx < mend) {
                    int p = sorted[sidx];
                    ushort* ar = act + (size_t)p * 1024 + n0 + wc * 32;
                    #pragma unroll
                    for (int ni = 0; ni < 2; ++ni) {
                        float g = ag[mi][ni][j], u = au[mi][ni][j];
                        float v = g / (1.f + __expf(-g)) * u;
                        ar[ni * 16 + fr] = f2bf(v);
                    }
                }
            }
        }
    }
}

// ---------------- down GEMM: A bf16 (linear LDS), B fp32 (swizzled) + atomic weighted moe_sum ----------------
__global__ __launch_bounds__(256) void k_gemm_dn(
    const ushort* __restrict__ act, const float* __restrict__ w2,
    const ushort* __restrict__ tmpde, const float* __restrict__ dbbe,
    const float* __restrict__ tw, float* __restrict__ out,
    const int* __restrict__ sorted, const int* __restrict__ offs)
{
    __shared__ ushort As[2][128 * 32];
    __shared__ float  Bf[2][64 * 32];
    const int tid = threadIdx.x, lane = tid & 63, wave = tid >> 6;
    const int wr = wave >> 1, wc = wave & 1;
    const int fr = lane & 15, q = lane >> 4;

    int off[Ed + 1], mt[Ed], pre[Ed + 1];
    #pragma unroll
    for (int e = 0; e <= Ed; ++e) off[e] = offs[e];
    pre[0] = 0;
    #pragma unroll
    for (int e = 0; e < Ed; ++e) {
        mt[e] = (off[e + 1] - off[e] + 127) / 128;
        pre[e + 1] = pre[e] + mt[e] * 16;          // 16 n-tiles of 64 cols
    }
    const int tot = pre[Ed];

    for (int bid = blockIdx.x; bid < tot; bid += gridDim.x) {
        int qq = tot >> 3, rr = tot & 7, x = bid & 7, ii = bid >> 3;
        int tau = (x < rr) ? x * (qq + 1) + ii : rr * (qq + 1) + (x - rr) * qq + ii;
        int e = 0;
        while (tau >= pre[e + 1]) ++e;
        int local = tau - pre[e];
        int nt = local / mt[e];
        int mtile = local - nt * mt[e];
        const int m0 = off[e] + mtile * 128;
        const int mend = off[e + 1];
        const int n0 = nt * 64;

        // A (bf16, linear): slot s -> row s>>2, kchunk s&3
        const ushort *as[2], *aes[2];
        #pragma unroll
        for (int r = 0; r < 2; ++r) {
            int s = r * 256 + tid;
            int srow = s >> 2, si = s & 3;
            int aIdx = m0 + srow; if (aIdx > mend - 1) aIdx = mend - 1;
            int p = sorted[aIdx];
            as[r]  = act + (size_t)p * 1024 + si * 8;
            aes[r] = tmpde + (size_t)p * 64 + si * 8;
        }
        // B (fp32, swizzled): slot s -> row s>>3, si=(s&7)^(srow&7)
        const float *bs[2], *bes[2];
        #pragma unroll
        for (int r = 0; r < 2; ++r) {
            int s = r * 256 + tid;
            int srow = s >> 3, si = (s & 7) ^ (srow & 7);
            bs[r]  = w2 + ((size_t)e * Hd + n0 + srow) * 1024 + si * 4;
            bes[r] = dbbe + ((size_t)(e * Hd + n0 + srow)) * 64 + si * 4;
        }

        f32x4 acc[4][2] = {};

        auto stage = [&](int s, int buf) {
            if (s < 32) {
                int k0 = s * 32;
                #pragma unroll
                for (int r = 0; r < 2; ++r) {
                    GLOAD_LDS16(as[r] + k0, (char*)&As[buf][0] + (r * 256 + wave * 64) * 16);
                    GLOAD_LDS16(bs[r] + k0, (char*)&Bf[buf][0] + (r * 256 + wave * 64) * 16);
                }
            } else {
                int k0 = (s - 32) * 32;
                #pragma unroll
                for (int r = 0; r < 2; ++r) {
                    GLOAD_LDS16(aes[r] + k0, (char*)&As[buf][0] + (r * 256 + wave * 64) * 16);
                    GLOAD_LDS16(bes[r] + k0, (char*)&Bf[buf][0] + (r * 256 + wave * 64) * 16);
                }
            }
        };
        auto step = [&](int buf) {
            bf16x8 afv[4], bv[2];
            #pragma unroll
            for (int mi = 0; mi < 4; ++mi) {
                int R = wr * 64 + mi * 16 + fr;
                afv[mi] = *(const bf16x8*)((const char*)&As[buf][0] + R * 64 + q * 16);
            }
            #pragma unroll
            for (int ni = 0; ni < 2; ++ni) {
                int R = wc * 32 + ni * 16 + fr;
                const float4* bb = (const float4*)&Bf[buf][R * 32];
                bv[ni] = pack8(bb[(2 * q) ^ (R & 7)], bb[(2 * q + 1) ^ (R & 7)]);
            }
            #pragma unroll
            for (int mi = 0; mi < 4; ++mi)
                #pragma unroll
                for (int ni = 0; ni < 2; ++ni)
                    acc[mi][ni] = __builtin_amdgcn_mfma_f32_16x16x32_bf16(afv[mi], bv[ni], acc[mi][ni], 0, 0, 0);
        };

        stage(0, 0);
        __syncthreads();
        int buf = 0;
        for (int s = 0; s < 34; ++s) {
            if (s < 33) stage(s + 1, buf ^ 1);
            step(buf);
            __syncthreads();
            buf ^= 1;
        }

        const int rb = wr * 64 + (lane >> 4) * 4;
        #pragma unroll
        for (int mi = 0; mi < 4; ++mi) {
            #pragma unroll
            for (int j = 0; j < 4; ++j) {
                int sidx = m0 + rb + mi * 16 + j;
                if (sidx < mend) {
                    int p = sorted[sidx];
                    float w = tw[p];
                    float* orow = out + (size_t)(p >> 1) * 1024 + n0 + wc * 32;
                    #pragma unroll
                    for (int ni = 0; ni < 2; ++ni)
                        atomicAdd(&orow[ni * 16 + fr], w * acc[mi][ni][j]);
                }
            }
        }
    }
}

extern "C" void kernel_launch(void* const* d_in, const int* in_sizes, int n_in,
                              void* d_out, int out_size, void* d_ws, size_t ws_size,
                              hipStream_t stream) {
    const float* hid  = (const float*)d_in[0];
    const float* tw   = (const float*)d_in[1];
    const float* w13  = (const float*)d_in[2];
    const float* w2   = (const float*)d_in[3];
    const float* ga   = (const float*)d_in[4];
    const float* gb   = (const float*)d_in[5];
    const float* da   = (const float*)d_in[6];
    const float* db   = (const float*)d_in[7];
    const float* sc   = (const float*)d_in[8];
    const int*   tids = (const int*)d_in[9];
    const int*   lidx = (const int*)d_in[10];
    float* out = (float*)d_out;

    char* ws = (char*)d_ws;
    float*  gbbe   = (float*)(ws);                           // 4 MB
    float*  dbbe   = (float*)(ws + (4ull << 20));            // 2 MB
    float*  tmp1e  = (float*)(ws + (6ull << 20));            // 512 KB
    ushort* tmpde  = (ushort*)(ws + (6ull << 20) + (512u << 10)); // 256 KB
    ushort* act    = (ushort*)(ws + (7ull << 20));           // 4 MB
    int*    sorted = (int*)(ws + (11ull << 20));             // 8 KB
    int*    offs   = (int*)(ws + (11ull << 20) + TKd * 4);   // 36 B

    k_prep<<<PREP_BLOCKS, 256, 0, stream>>>(hid, gb, db, ga, sc, tids, lidx,
                                            gbbe, dbbe, tmp1e, out, sorted, offs);
    k_gemm_gu<<<512, 256, 0, stream>>>(hid, w13, tmp1e, gbbe, act, sorted, offs);
    k_tmp_dn<<<TKd, 256, 0, stream>>>(act, da, sc, tids, lidx, tmpde);
    k_gemm_dn<<<512, 256, 0, stream>>>(act, w2, tmpde, dbbe, tw, out, sorted, offs);
}

// Round 9
// 103.111 us; speedup vs baseline: 1.5170x; 1.5170x over previous
//
#include <hip/hip_runtime.h>
#include <stdint.h>

#define Td 1024
#define Hd 1024
#define Id 1024
#define Ed 8
#define Kd 2
#define Ld 4
#define Rd 16
#define Nd 2048
#define TKd (Td*Kd)

typedef __bf16 bf16x8 __attribute__((ext_vector_type(8)));
typedef float f32x4 __attribute__((ext_vector_type(4)));

__device__ __forceinline__ ushort f2bf(float f) {
    uint32_t u = __builtin_bit_cast(uint32_t, f);
    return (ushort)((u + 0x7fffu + ((u >> 16) & 1u)) >> 16);
}
__device__ __forceinline__ float bf2f(ushort u) {
    uint32_t x = ((uint32_t)u) << 16;
    return __builtin_bit_cast(float, x);
}
// 16 consecutive fp32 -> 16 bf16 (64B read, 32B write)
__device__ __forceinline__ void cvt16(const float* __restrict__ s, ushort* __restrict__ d) {
    float4 a0 = *(const float4*)(s);
    float4 a1 = *(const float4*)(s + 4);
    float4 a2 = *(const float4*)(s + 8);
    float4 a3 = *(const float4*)(s + 12);
    uint4 o0, o1;
    o0.x = (uint)f2bf(a0.x) | ((uint)f2bf(a0.y) << 16);
    o0.y = (uint)f2bf(a0.z) | ((uint)f2bf(a0.w) << 16);
    o0.z = (uint)f2bf(a1.x) | ((uint)f2bf(a1.y) << 16);
    o0.w = (uint)f2bf(a1.z) | ((uint)f2bf(a1.w) << 16);
    o1.x = (uint)f2bf(a2.x) | ((uint)f2bf(a2.y) << 16);
    o1.y = (uint)f2bf(a2.z) | ((uint)f2bf(a2.w) << 16);
    o1.z = (uint)f2bf(a3.x) | ((uint)f2bf(a3.y) << 16);
    o1.w = (uint)f2bf(a3.z) | ((uint)f2bf(a3.w) << 16);
    *(uint4*)(d) = o0;
    *(uint4*)(d + 8) = o1;
}

#define GLOAD_LDS16(g, l) __builtin_amdgcn_global_load_lds( \
    (const __attribute__((address_space(1))) uint32_t*)(const void*)(g), \
    (__attribute__((address_space(3))) uint32_t*)(void*)(l), 16, 0, 0)

// block-role partition of k_prep (w2 conversion rides inside k_gemm_gu)
#define W13C 4096  // w13 fp32->bf16, 16 floats/thread
#define TB 2048    // gate_up LoRA-A projection (one per pair)
#define XB 256     // x convert, 16 floats/thread
#define CB 384     // LoRA-B interleave (rows of 16)
#define ZB 1024    // out zeroing
#define PREP_BLOCKS (W13C + TB + XB + CB + ZB + 1)

__global__ __launch_bounds__(256) void k_prep(
    const float* __restrict__ hid, const float* __restrict__ w13,
    const float* __restrict__ gb, const float* __restrict__ db,
    const float* __restrict__ ga, const float* __restrict__ sc,
    const int* __restrict__ tids, const int* __restrict__ lidx,
    ushort* __restrict__ xb, ushort* __restrict__ w13b,
    ushort* __restrict__ gbbe, ushort* __restrict__ dbbe, ushort* __restrict__ tmp1e,
    float* __restrict__ out, int* __restrict__ sorted, int* __restrict__ offs)
{
    __shared__ float tr[Rd];
    __shared__ int cnt[Ed];
    __shared__ int cur[Ed];
    const int b = blockIdx.x, tid = threadIdx.x;

    if (b < W13C) {
        // ---- w13 fp32 -> bf16 ----
        size_t off = ((size_t)b * 256 + tid) * 16;
        cvt16(w13 + off, w13b + off);
    } else if (b < W13C + TB) {
        // ---- gate_up LoRA-A projection: tmp1e[p][l*16+r] = s*(Ag[l,e]@x[t]) ----
        const int p = b - W13C;
        const int e = tids[p];
        const int l = lidx[p >> 1];
        const float s = sc[l];
        const int r = tid >> 4, q = tid & 15;
        const float* A = ga + (((size_t)l * Ed + e) * Rd + r) * 1024;
        const float* x = hid + (size_t)(p >> 1) * 1024;
        float sum = 0.f;
        #pragma unroll
        for (int i = 0; i < 16; ++i) {
            int h = q * 4 + 64 * i;
            float4 a = *(const float4*)(A + h);
            float4 v = *(const float4*)(x + h);
            sum += a.x * v.x + a.y * v.y + a.z * v.z + a.w * v.w;
        }
        sum += __shfl_xor(sum, 1); sum += __shfl_xor(sum, 2);
        sum += __shfl_xor(sum, 4); sum += __shfl_xor(sum, 8);
        if (q == 0) tr[r] = sum;
        __syncthreads();
        if (tid < 32) {
            int j0 = tid * 2;
            uint v = 0;
            if ((j0 >> 4) == l)
                v = (uint)f2bf(s * tr[j0 & 15]) | ((uint)f2bf(s * tr[(j0 + 1) & 15]) << 16);
            ((uint*)(tmp1e + (size_t)p * 64))[tid] = v;
        }
    } else if (b < W13C + TB + XB) {
        // ---- x fp32 -> bf16 ----
        size_t off = ((size_t)(b - W13C - TB) * 256 + tid) * 16;
        cvt16(hid + off, xb + off);
    } else if (b < W13C + TB + XB + CB) {
        // ---- LoRA-B l-interleave: gbbe[e][n][l*16+r] = gb[l][e][n][r] (same for db) ----
        constexpr int GR = Ld * Ed * Nd;
        int i = (b - W13C - TB - XB) * 256 + tid;
        const float* src; ushort* dst;
        if (i < GR) {
            int l = i >> 14, e = (i >> 11) & 7, n = i & 2047;
            src = gb + (size_t)i * 16;
            dst = gbbe + ((size_t)(e * Nd + n)) * 64 + l * 16;
        } else {
            int j = i - GR;
            int l = j >> 13, e = (j >> 10) & 7, n = j & 1023;
            src = db + (size_t)j * 16;
            dst = dbbe + ((size_t)(e * Id + n)) * 64 + l * 16;
        }
        cvt16(src, dst);
    } else if (b < W13C + TB + XB + CB + ZB) {
        // ---- zero out (atomic accumulation target) ----
        int i = (b - W13C - TB - XB - CB) * 256 + tid;
        ((float4*)out)[i] = make_float4(0.f, 0.f, 0.f, 0.f);
    } else {
        // ---- route sort (single block, 8 pairs/thread) ----
        if (tid < Ed) cnt[tid] = 0;
        __syncthreads();
        int el[8];
        #pragma unroll
        for (int i = 0; i < 8; ++i) {
            el[i] = tids[tid + i * 256];
            atomicAdd(&cnt[el[i]], 1);
        }
        __syncthreads();
        if (tid == 0) {
            int s = 0;
            for (int e = 0; e < Ed; ++e) { offs[e] = s; cur[e] = s; s += cnt[e]; }
            offs[Ed] = s;
        }
        __syncthreads();
        #pragma unroll
        for (int i = 0; i < 8; ++i) {
            int pos = atomicAdd(&cur[el[i]], 1);
            sorted[pos] = tid + i * 256;
        }
    }
}

// ---------------- down LoRA-A projection (act bf16 input) ----------------
__global__ __launch_bounds__(256) void k_tmp_dn(
    const ushort* __restrict__ act, const float* __restrict__ da,
    const float* __restrict__ sc, const int* __restrict__ tids,
    const int* __restrict__ lidx, ushort* __restrict__ tmpde)
{
    const int p = blockIdx.x;
    const int e = tids[p];
    const int l = lidx[p >> 1];
    const float s = sc[l];
    const int tid = threadIdx.x;
    const int r = tid >> 4, q = tid & 15;
    const float* A = da + (((size_t)l * Ed + e) * Rd + r) * 1024;
    const ushort* x = act + (size_t)p * 1024;
    float sum = 0.f;
    #pragma unroll
    for (int i = 0; i < 8; ++i) {
        int h = q * 8 + 128 * i;
        float4 a0 = *(const float4*)(A + h);
        float4 a1 = *(const float4*)(A + h + 4);
        ushort4 v0 = *(const ushort4*)(x + h);
        ushort4 v1 = *(const ushort4*)(x + h + 4);
        sum += a0.x * bf2f(v0.x) + a0.y * bf2f(v0.y) + a0.z * bf2f(v0.z) + a0.w * bf2f(v0.w)
             + a1.x * bf2f(v1.x) + a1.y * bf2f(v1.y) + a1.z * bf2f(v1.z) + a1.w * bf2f(v1.w);
    }
    sum += __shfl_xor(sum, 1); sum += __shfl_xor(sum, 2);
    sum += __shfl_xor(sum, 4); sum += __shfl_xor(sum, 8);
    __shared__ float tr[Rd];
    if (q == 0) tr[r] = sum;
    __syncthreads();
    if (tid < 32) {
        int j0 = tid * 2;
        uint v = 0;
        if ((j0 >> 4) == l)
            v = (uint)f2bf(s * tr[j0 & 15]) | ((uint)f2bf(s * tr[(j0 + 1) & 15]) << 16);
        ((uint*)(tmpde + (size_t)p * 64))[tid] = v;
    }
}

// ---------------- gate_up GEMM (R6 structure) + w2-convert rider blocks ----------------
#define GUB 512   // GEMM blocks; blocks >= GUB convert w2
#define W2C 2048  // w2 convert blocks (16 floats/thread)

__global__ __launch_bounds__(256) void k_gemm_gu(
    const ushort* __restrict__ xb, const ushort* __restrict__ w13b,
    const ushort* __restrict__ tmp1e, const ushort* __restrict__ gbbe,
    const float* __restrict__ w2, ushort* __restrict__ w2b,
    ushort* __restrict__ act, const int* __restrict__ sorted,
    const int* __restrict__ offs)
{
    __shared__ ushort As[128][32];
    __shared__ ushort Bs[128][32];
    const int tid = threadIdx.x;

    if (blockIdx.x >= GUB) {
        // ---- rider: w2 fp32 -> bf16 (overlaps GEMM; consumed only by k_gemm_dn) ----
        size_t off = ((size_t)(blockIdx.x - GUB) * 256 + tid) * 16;
        cvt16(w2 + off, w2b + off);
        return;
    }

    const int lane = tid & 63, wave = tid >> 6;
    const int wr = wave >> 1, wc = wave & 1;
    const int fr = lane & 15, fk = (lane >> 4) * 8;

    int off[Ed + 1];
    #pragma unroll
    for (int e = 0; e <= Ed; ++e) off[e] = offs[e];
    int mt[Ed]; int tot = 0;
    #pragma unroll
    for (int e = 0; e < Ed; ++e) {
        mt[e] = (off[e + 1] - off[e] + 127) / 128;
        tot += mt[e] * 16;
    }

    for (int tau = blockIdx.x; tau < tot; tau += GUB) {
        int t = tau, e = 0;
        while (t >= mt[e] * 16) { t -= mt[e] * 16; ++e; }
        const int m0 = off[e] + (t >> 4) * 128;
        const int mend = off[e + 1];
        const int n0 = (t & 15) * 64;

        const ushort *asrc[2], *aesrc[2], *bsrc[2], *besrc[2];
        #pragma unroll
        for (int r = 0; r < 2; ++r) {
            int c = r * 256 + tid;
            int row = c >> 2, kc = c & 3;
            int aIdx = m0 + row; if (aIdx > mend - 1) aIdx = mend - 1;
            int p = sorted[aIdx];
            asrc[r]  = xb + (size_t)(p >> 1) * 1024 + kc * 8;
            aesrc[r] = tmp1e + (size_t)p * 64 + kc * 8;
            int grow = (row < 64) ? (n0 + row) : (1024 + n0 + row - 64);
            bsrc[r]  = w13b + ((size_t)e * Nd + grow) * 1024 + kc * 8;
            besrc[r] = gbbe + ((size_t)e * Nd + grow) * 64 + kc * 8;
        }

        f32x4 ag[4][2] = {}, au[4][2] = {};
        auto step = [&]() {
            bf16x8 af[4], bg[2], bu[2];
            #pragma unroll
            for (int mi = 0; mi < 4; ++mi)
                af[mi] = *(const bf16x8*)(&As[wr * 64 + mi * 16 + fr][fk]);
            #pragma unroll
            for (int ni = 0; ni < 2; ++ni) {
                bg[ni] = *(const bf16x8*)(&Bs[wc * 32 + ni * 16 + fr][fk]);
                bu[ni] = *(const bf16x8*)(&Bs[64 + wc * 32 + ni * 16 + fr][fk]);
            }
            #pragma unroll
            for (int mi = 0; mi < 4; ++mi)
                #pragma unroll
                for (int ni = 0; ni < 2; ++ni) {
                    ag[mi][ni] = __builtin_amdgcn_mfma_f32_16x16x32_bf16(af[mi], bg[ni], ag[mi][ni], 0, 0, 0);
                    au[mi][ni] = __builtin_amdgcn_mfma_f32_16x16x32_bf16(af[mi], bu[ni], au[mi][ni], 0, 0, 0);
                }
        };

        for (int k0 = 0; k0 < 1024; k0 += 32) {
            #pragma unroll
            for (int r = 0; r < 2; ++r) {
                GLOAD_LDS16(asrc[r] + k0, (char*)&As[0][0] + (r * 256 + wave * 64) * 16);
                GLOAD_LDS16(bsrc[r] + k0, (char*)&Bs[0][0] + (r * 256 + wave * 64) * 16);
            }
            __syncthreads();
            step();
            __syncthreads();
        }
        #pragma unroll
        for (int es = 0; es < 2; ++es) {
            #pragma unroll
            for (int r = 0; r < 2; ++r) {
                GLOAD_LDS16(aesrc[r] + es * 32, (char*)&As[0][0] + (r * 256 + wave * 64) * 16);
                GLOAD_LDS16(besrc[r] + es * 32, (char*)&Bs[0][0] + (r * 256 + wave * 64) * 16);
            }
            __syncthreads();
            step();
            __syncthreads();
        }

        // epilogue: fused silu_and_mul -> act bf16
        const int rb = wr * 64 + (lane >> 4) * 4;
        #pragma unroll
        for (int mi = 0; mi < 4; ++mi) {
            #pragma unroll
            for (int j = 0; j < 4; ++j) {
                int sidx = m0 + rb + mi * 16 + j;
                if (sidx < mend) {
                    int p = sorted[sidx];
                    ushort* ar = act + (size_t)p * 1024 + n0 + wc * 32;
                    #pragma unroll
                    for (int ni = 0; ni < 2; ++ni) {
                        float g = ag[mi][ni][j], u = au[mi][ni][j];
                        float v = g / (1.f + __expf(-g)) * u;
                        ar[ni * 16 + fr] = f2bf(v);
                    }
                }
            }
        }
    }
}

// ---------------- down GEMM (R6 structure) + LoRA-B ext + atomic weighted moe_sum ----------------
__global__ __launch_bounds__(256) void k_gemm_dn(
    const ushort* __restrict__ act, const ushort* __restrict__ w2b,
    const ushort* __restrict__ tmpde, const ushort* __restrict__ dbbe,
    const float* __restrict__ tw, float* __restrict__ out,
    const int* __restrict__ sorted, const int* __restrict__ offs)
{
    __shared__ ushort As[128][32];
    __shared__ ushort Bs[64][32];
    const int tid = threadIdx.x, lane = tid & 63, wave = tid >> 6;
    const int wr = wave >> 1, wc = wave & 1;
    const int fr = lane & 15, fk = (lane >> 4) * 8;

    int off[Ed + 1];
    #pragma unroll
    for (int e = 0; e <= Ed; ++e) off[e] = offs[e];
    int mt[Ed]; int tot = 0;
    #pragma unroll
    for (int e = 0; e < Ed; ++e) {
        mt[e] = (off[e + 1] - off[e] + 127) / 128;
        tot += mt[e] * 16;
    }

    for (int tau = blockIdx.x; tau < tot; tau += gridDim.x) {
        int t = tau, e = 0;
        while (t >= mt[e] * 16) { t -= mt[e] * 16; ++e; }
        const int m0 = off[e] + (t >> 4) * 128;
        const int mend = off[e + 1];
        const int n0 = (t & 15) * 64;

        const ushort *asrc[2], *aesrc[2];
        #pragma unroll
        for (int r = 0; r < 2; ++r) {
            int c = r * 256 + tid;
            int row = c >> 2, kc = c & 3;
            int aIdx = m0 + row; if (aIdx > mend - 1) aIdx = mend - 1;
            int p = sorted[aIdx];
            asrc[r]  = act + (size_t)p * 1024 + kc * 8;
            aesrc[r] = tmpde + (size_t)p * 64 + kc * 8;
        }
        const ushort *bsrc, *besrc;
        {
            int row = tid >> 2, kc = tid & 3;
            bsrc  = w2b + ((size_t)e * Hd + n0 + row) * 1024 + kc * 8;
            besrc = dbbe + ((size_t)e * Hd + n0 + row) * 64 + kc * 8;
        }

        f32x4 acc[4][2] = {};
        auto step = [&]() {
            bf16x8 af[4], bv[2];
            #pragma unroll
            for (int mi = 0; mi < 4; ++mi)
                af[mi] = *(const bf16x8*)(&As[wr * 64 + mi * 16 + fr][fk]);
            #pragma unroll
            for (int ni = 0; ni < 2; ++ni)
                bv[ni] = *(const bf16x8*)(&Bs[wc * 32 + ni * 16 + fr][fk]);
            #pragma unroll
            for (int mi = 0; mi < 4; ++mi)
                #pragma unroll
                for (int ni = 0; ni < 2; ++ni)
                    acc[mi][ni] = __builtin_amdgcn_mfma_f32_16x16x32_bf16(af[mi], bv[ni], acc[mi][ni], 0, 0, 0);
        };

        for (int k0 = 0; k0 < 1024; k0 += 32) {
            #pragma unroll
            for (int r = 0; r < 2; ++r)
                GLOAD_LDS16(asrc[r] + k0, (char*)&As[0][0] + (r * 256 + wave * 64) * 16);
            GLOAD_LDS16(bsrc + k0, (char*)&Bs[0][0] + (wave * 64) * 16);
            __syncthreads();
            step();
            __syncthreads();
        }
        #pragma unroll
        for (int es = 0; es < 2; ++es) {
            #pragma unroll
            for (int r = 0; r < 2; ++r)
                GLOAD_LDS16(aesrc[r] + es * 32, (char*)&As[0][0] + (r * 256 + wave * 64) * 16);
            GLOAD_LDS16(besrc + es * 32, (char*)&Bs[0][0] + (wave * 64) * 16);
            __syncthreads();
            step();
            __syncthreads();
        }

        const int rb = wr * 64 + (lane >> 4) * 4;
        #pragma unroll
        for (int mi = 0; mi < 4; ++mi) {
            #pragma unroll
            for (int j = 0; j < 4; ++j) {
                int sidx = m0 + rb + mi * 16 + j;
                if (sidx < mend) {
                    int p = sorted[sidx];
                    float w = tw[p];
                    float* orow = out + (size_t)(p >> 1) * 1024 + n0 + wc * 32;
                    #pragma unroll
                    for (int ni = 0; ni < 2; ++ni)
                        atomicAdd(&orow[ni * 16 + fr], w * acc[mi][ni][j]);
                }
            }
        }
    }
}

extern "C" void kernel_launch(void* const* d_in, const int* in_sizes, int n_in,
                              void* d_out, int out_size, void* d_ws, size_t ws_size,
                              hipStream_t stream) {
    const float* hid  = (const float*)d_in[0];
    const float* tw   = (const float*)d_in[1];
    const float* w13  = (const float*)d_in[2];
    const float* w2   = (const float*)d_in[3];
    const float* ga   = (const float*)d_in[4];
    const float* gb   = (const float*)d_in[5];
    const float* da   = (const float*)d_in[6];
    const float* db   = (const float*)d_in[7];
    const float* sc   = (const float*)d_in[8];
    const int*   tids = (const int*)d_in[9];
    const int*   lidx = (const int*)d_in[10];
    float* out = (float*)d_out;

    char* ws = (char*)d_ws;
    ushort* xb     = (ushort*)(ws);                          // 2 MB
    ushort* w13b   = (ushort*)(ws + (2ull  << 20));          // 32 MB
    ushort* w2b    = (ushort*)(ws + (34ull << 20));          // 16 MB
    ushort* gbbe   = (ushort*)(ws + (50ull << 20));          // 2 MB
    ushort* dbbe   = (ushort*)(ws + (52ull << 20));          // 1 MB
    ushort* tmp1e  = (ushort*)(ws + (53ull << 20));          // 256 KB
    ushort* tmpde  = (ushort*)(ws + (53ull << 20) + (256u << 10)); // 256 KB
    ushort* act    = (ushort*)(ws + (54ull << 20));          // 4 MB
    int*    sorted = (int*)(ws + (58ull << 20));             // 8 KB
    int*    offs   = (int*)(ws + (58ull << 20) + TKd * 4);   // 36 B

    k_prep<<<PREP_BLOCKS, 256, 0, stream>>>(hid, w13, gb, db, ga, sc, tids, lidx,
                                            xb, w13b, gbbe, dbbe, tmp1e, out, sorted, offs);
    k_gemm_gu<<<GUB + W2C, 256, 0, stream>>>(xb, w13b, tmp1e, gbbe, w2, w2b, act, sorted, offs);
    k_tmp_dn<<<TKd, 256, 0, stream>>>(act, da, sc, tids, lidx, tmpde);
    k_gemm_dn<<<512, 256, 0, stream>>>(act, w2b, tmpde, dbbe, tw, out, sorted, offs);
}